// Round 1
// baseline (1531.031 us; speedup 1.0000x reference)
//
#include <hip/hip_runtime.h>

// Soft-DTW, gamma=1.0, B=64, N=M=1024.
// One workgroup (1024 threads) per batch. Anti-diagonal wavefront:
// thread t holds diag-vector entries i=t+1 of the two previous diagonals in
// registers; neighbor values (i-1 = t) come from thread t-1 via LDS with one
// barrier per step. D is staged in LDS in skewed bands of C=8 diagonals.
// DP runs in log2-scaled domain (v' = v*log2(e)) so softmin is pure exp2/log2.

#define BIGV 1.0e10f
#define LOG2E 1.4426950408889634f

constexpr int N = 1024;
constexpr int TPB = 1024;
constexpr int C = 8;            // diagonals per super-step
constexpr int TSTRIDE = C + 1;  // LDS tile row stride (9 floats -> conflict-free)

__global__ __launch_bounds__(TPB)
void softdtw_kernel(const float* __restrict__ D, float* __restrict__ out) {
    const int b = blockIdx.x;
    const int t = threadIdx.x;
    const float* Db = D + (size_t)b * N * N;

    __shared__ float tile[N * TSTRIDE];   // 36,864 B skewed D band
    __shared__ float xch1[2][TPB];        // prev-diag boundary exchange
    __shared__ float xch2[2][TPB];        // prev-prev-diag boundary exchange

    // p1 = v_{d-1}[i], p2 = v_{d-2}[i]; start at d=2: v_1 = v_0 = BIG (i>=1)
    float p1 = BIGV, p2 = BIGV;
    int par = 0;

    const int nsuper = (2 * N) / C;  // 256 super-steps cover d = 2 .. 2N(+1 guarded)
    for (int s = 0; s < nsuper; ++s) {
        const int dstart = 2 + s * C;

        // ---- stage D band: tile[t][c] = D[t][dstart-2-t+c] (clamped) ----
        __syncthreads();  // previous super-step's tile reads complete
        {
            const int j0 = dstart - 2 - t;
            #pragma unroll
            for (int c = 0; c < C; ++c) {
                int j = j0 + c;
                int jc = min(max(j, 0), N - 1);   // clamp; invalid cells masked later
                tile[t * TSTRIDE + c] = Db[(size_t)t * N + jc];
            }
        }
        __syncthreads();

        // ---- C diagonal steps ----
        for (int c = 0; c < C; ++c) {
            const int d = dstart + c;
            if (d > 2 * N) break;            // uniform across block

            float dv = tile[t * TSTRIDE + c];

            xch1[par][t] = p1;
            xch2[par][t] = p2;
            __syncthreads();

            float nb1, nb2;                  // v_{d-1}[i-1], v_{d-2}[i-1]
            if (t == 0) {
                nb1 = BIGV;
                nb2 = (d == 2) ? 0.0f : BIGV;   // corner R[0][0]=0 enters at d=2
            } else {
                nb1 = xch1[par][t - 1];
                nb2 = xch2[par][t - 1];
            }

            // softmin3 in log2 domain: sm = mn - log2(2^(mn-a)+2^(mn-b)+2^(mn-c))
            float aa = nb2, bb = nb1, cc = p1;
            float mn = fminf(fminf(aa, bb), cc);
            float ssum = exp2f(mn - aa) + exp2f(mn - bb) + exp2f(mn - cc);
            float sm = mn - log2f(ssum);

            int j = d - 2 - t;               // D column for this cell
            bool valid = (j >= 0) && (j < N);
            float nv = valid ? fmaf(dv, LOG2E, sm) : BIGV;

            p2 = p1;
            p1 = nv;
            par ^= 1;
        }
    }

    // answer: v_{2N}[N] held by thread N-1; unscale from log2 domain
    if (t == TPB - 1) out[b] = p1 * (1.0f / LOG2E);
}

extern "C" void kernel_launch(void* const* d_in, const int* in_sizes, int n_in,
                              void* d_out, int out_size, void* d_ws, size_t ws_size,
                              hipStream_t stream) {
    const float* D = (const float*)d_in[0];
    float* out = (float*)d_out;
    const int B = in_sizes[0] / (N * N);
    softdtw_kernel<<<B, TPB, 0, stream>>>(D, out);
}